// Round 4
// baseline (335.577 us; speedup 1.0000x reference)
//
#include <hip/hip_runtime.h>
#include <hip/hip_bf16.h>

#define H 16
#define DM 1024
#define DK 64
#define B_ 4
#define N_ 2048

typedef __attribute__((ext_vector_type(8))) short bf16x8;
typedef __attribute__((ext_vector_type(4))) short s16x4;
typedef __attribute__((ext_vector_type(2))) unsigned int u32x2;
typedef __attribute__((ext_vector_type(4))) float f32x4;

static __device__ __forceinline__ short f2bs(float x) {
    __hip_bfloat16 b = __float2bfloat16(x);
    return *reinterpret_cast<short*>(&b);
}

// async 16B global -> LDS (LDS side is wave base + lane*16)
static __device__ __forceinline__ void async16(const void* g, void* l) {
    __builtin_amdgcn_global_load_lds(
        (const __attribute__((address_space(1))) void*)g,
        (__attribute__((address_space(3))) void*)l, 16, 0, 0);
}

// pack two fp32 -> two bf16 (truncation) in one v_perm_b32
static __device__ __forceinline__ unsigned packbf(float lo, float hi) {
    return __builtin_amdgcn_perm(__float_as_uint(hi), __float_as_uint(lo), 0x07060302u);
}

// ---------------------------------------------------------------------------
// Weight prep only (QKV convert now fused into proj_gemm's A staging).
// 1024 blocks: z<3 -> Wq/Wk/Wv transpose, z==3 -> Wo transpose.
// ---------------------------------------------------------------------------
__global__ __launch_bounds__(256) void prep_w(
    const float* __restrict__ Wq, const float* __restrict__ Wk,
    const float* __restrict__ Wv, const float* __restrict__ Wo,
    short* __restrict__ wqT, short* __restrict__ wkT,
    short* __restrict__ wvT, short* __restrict__ woT)
{
    __shared__ float tile[64][65];
    int z = blockIdx.x >> 8;
    int bx = blockIdx.x & 255;
    int t = threadIdx.x;
    int tj = t & 63, ti = t >> 6;

    if (z < 3) {
        const float* src = (z == 0) ? Wq : (z == 1) ? Wk : Wv;
        short* dst = (z == 0) ? wqT : (z == 1) ? wkT : wvT;
        int h = bx >> 4;
        int dmt = bx & 15;
        #pragma unroll
        for (int r = 0; r < 16; ++r) {
            int i = r * 4 + ti;
            tile[i][tj] = src[((size_t)h * 1024 + dmt * 64 + i) * 64 + tj];
        }
        __syncthreads();
        #pragma unroll
        for (int r = 0; r < 16; ++r) {
            int dk = r * 4 + ti;
            dst[((size_t)h * 64 + dk) * 1024 + dmt * 64 + tj] = f2bs(tile[tj][dk]);
        }
    } else {
        int kt = bx >> 4;
        int nt = bx & 15;
        #pragma unroll
        for (int r = 0; r < 16; ++r) {
            int i = r * 4 + ti;
            tile[i][tj] = Wo[((size_t)kt * 64 + i) * 1024 + nt * 64 + tj];
        }
        __syncthreads();
        #pragma unroll
        for (int r = 0; r < 16; ++r) {
            int jn = r * 4 + ti;
            woT[((size_t)nt * 64 + jn) * 1024 + kt * 64 + tj] = f2bs(tile[tj][jn]);
        }
    }
}

// ---------------------------------------------------------------------------
// GEMM mainloop with fused f32->bf16 A-convert (proj only).
// A side: reg-staged from ORIGINAL f32 source (T14 issue-early/write-late):
//   loads for tile t+2 issued at step t, converted (RNE, bit-identical to
//   old prep) + ds_written at step t+1, consumed at t+2.
// B side: async global_load_lds as before. 3 x 16KB rotating bufs.
// Per step: s_waitcnt vmcnt(6) lgkmcnt(0) -> s_barrier (publishes tile t:
// B via the vmcnt, A via last step's ds_writes + lgkm drain) -> ds_write
// A(t+1) (compiler's dep-wait = vmcnt(2), leaves B(t+1) in flight) ->
// issue A(t+2) f32 loads + B(t+2) asyncs -> compute tile t.
// LDS layout and bf16 values are bit-identical to the old path.
// ---------------------------------------------------------------------------
static __device__ __forceinline__ void gemm_mainloop_f32A(
    const float* __restrict__ Af, const short* __restrict__ BT,
    int rowM0, int colN0, char* lds, f32x4 (&acc)[4][4])
{
    int tid = threadIdx.x;
    int lane = tid & 63, w = tid >> 6;
    int l16 = lane & 15, quad = lane >> 4;
    int wm = w >> 1, wn = w & 1;
    int xg = (quad ^ ((l16 >> 1) & 3)) << 4;   // swizzled read slot

    int r0 = w * 32 + (lane >> 2);
    int gsl = ((lane & 3) ^ ((lane >> 3) & 3)) << 4;   // bf16 granule byte off
    int dst0 = w * 2048 + lane * 16;
    const char* Af0 = (const char*)Af + (size_t)(rowM0 + r0) * 4096 + gsl * 2;
    const char* Af1 = Af0 + (size_t)16 * 4096;
    const char* Bg0 = (const char*)BT + (size_t)(colN0 + r0) * 2048 + gsl;
    const char* Bg1 = Bg0 + 16 * 2048;

    f32x4 c00, c01, c10, c11;                  // carried A(t+1) f32 data

    // prologue: A(0)+B(0), write A(0)->buf0, A(1)+B(1)
    c00 = *(const f32x4*)(Af0);
    c01 = *(const f32x4*)(Af0 + 16);
    c10 = *(const f32x4*)(Af1);
    c11 = *(const f32x4*)(Af1 + 16);
    async16(Bg0, lds + 8192 + dst0);
    async16(Bg1, lds + 8192 + dst0 + 1024);
    {
        bf16x8 p0, p1;
        #pragma unroll
        for (int j = 0; j < 4; ++j) {
            p0[j] = f2bs(c00[j]); p0[4 + j] = f2bs(c01[j]);
            p1[j] = f2bs(c10[j]); p1[4 + j] = f2bs(c11[j]);
        }
        *(bf16x8*)(lds + dst0) = p0;
        *(bf16x8*)(lds + dst0 + 1024) = p1;
    }
    c00 = *(const f32x4*)(Af0 + 128);
    c01 = *(const f32x4*)(Af0 + 144);
    c10 = *(const f32x4*)(Af1 + 128);
    c11 = *(const f32x4*)(Af1 + 144);
    async16(Bg0 + 64, lds + 16384 + 8192 + dst0);
    async16(Bg1 + 64, lds + 16384 + 8192 + dst0 + 1024);

    int o0 = 0, o1 = 16384, o2 = 32768;        // consume / A-write / issue
    for (int it = 0; it < 32; ++it) {
        if (it < 31) asm volatile("s_waitcnt vmcnt(6) lgkmcnt(0)" ::: "memory");
        else         asm volatile("s_waitcnt vmcnt(0) lgkmcnt(0)" ::: "memory");
        __builtin_amdgcn_s_barrier();
        __builtin_amdgcn_sched_barrier(0);

        if (it + 1 < 32) {                     // convert + publish A(t+1)
            bf16x8 p0, p1;
            #pragma unroll
            for (int j = 0; j < 4; ++j) {
                p0[j] = f2bs(c00[j]); p0[4 + j] = f2bs(c01[j]);
                p1[j] = f2bs(c10[j]); p1[4 + j] = f2bs(c11[j]);
            }
            *(bf16x8*)(lds + o1 + dst0) = p0;
            *(bf16x8*)(lds + o1 + dst0 + 1024) = p1;
        }
        if (it + 2 < 32) {                     // issue tile t+2 (A first, B last)
            int fo = (it + 2) * 128;
            c00 = *(const f32x4*)(Af0 + fo);
            c01 = *(const f32x4*)(Af0 + fo + 16);
            c10 = *(const f32x4*)(Af1 + fo);
            c11 = *(const f32x4*)(Af1 + fo + 16);
            int bo2 = (it + 2) * 64;
            async16(Bg0 + bo2, lds + o2 + 8192 + dst0);
            async16(Bg1 + bo2, lds + o2 + 8192 + dst0 + 1024);
        }
        __builtin_amdgcn_sched_barrier(0);

        const char* As = lds + o0;
        const char* Bs = As + 8192;
        bf16x8 a[4], b[4];
        #pragma unroll
        for (int i = 0; i < 4; ++i)
            a[i] = *(const bf16x8*)(As + (wm * 64 + i * 16 + l16) * 64 + xg);
        #pragma unroll
        for (int j = 0; j < 4; ++j)
            b[j] = *(const bf16x8*)(Bs + (wn * 64 + j * 16 + l16) * 64 + xg);
        #pragma unroll
        for (int i = 0; i < 4; ++i)
            #pragma unroll
            for (int j = 0; j < 4; ++j)
                acc[i][j] = __builtin_amdgcn_mfma_f32_16x16x32_bf16(a[i], b[j], acc[i][j], 0, 0, 0);

        int tmp = o0; o0 = o1; o1 = o2; o2 = tmp;
    }
}

// ---------------------------------------------------------------------------
// GEMM mainloop, all-bf16 (out_gemm): unchanged counted-vmcnt single-barrier
// pipeline from round 3.
// ---------------------------------------------------------------------------
static __device__ __forceinline__ void gemm_mainloop(
    const short* __restrict__ A, const short* __restrict__ BT,
    int rowM0, int colN0, char* lds, f32x4 (&acc)[4][4])
{
    int tid = threadIdx.x;
    int lane = tid & 63, w = tid >> 6;
    int l16 = lane & 15, quad = lane >> 4;
    int wm = w >> 1, wn = w & 1;
    int xg = (quad ^ ((l16 >> 1) & 3)) << 4;   // swizzled read slot

    int r0 = w * 32 + (lane >> 2);
    int gsl = ((lane & 3) ^ ((lane >> 3) & 3)) << 4;
    int dst0 = w * 2048 + lane * 16;
    const char* Ag0 = (const char*)A + (size_t)(rowM0 + r0) * 2048 + gsl;
    const char* Ag1 = Ag0 + 16 * 2048;
    const char* Bg0 = (const char*)BT + (size_t)(colN0 + r0) * 2048 + gsl;
    const char* Bg1 = Bg0 + 16 * 2048;

    #pragma unroll
    for (int t = 0; t < 2; ++t) {
        size_t kb = (size_t)t * 64;
        char* As = lds + t * 16384;
        char* Bs = As + 8192;
        async16(Ag0 + kb, As + dst0);
        async16(Ag1 + kb, As + dst0 + 1024);
        async16(Bg0 + kb, Bs + dst0);
        async16(Bg1 + kb, Bs + dst0 + 1024);
    }

    int c0 = 0;
    int cr = 32768;
    for (int it = 0; it < 32; ++it) {
        if (it < 31) asm volatile("s_waitcnt vmcnt(4)" ::: "memory");
        else         asm volatile("s_waitcnt vmcnt(0)" ::: "memory");
        __builtin_amdgcn_s_barrier();
        __builtin_amdgcn_sched_barrier(0);

        if (it + 2 < 32) {
            size_t kb = (size_t)(it + 2) * 64;
            char* Aw = lds + cr;
            char* Bw = Aw + 8192;
            async16(Ag0 + kb, Aw + dst0);
            async16(Ag1 + kb, Aw + dst0 + 1024);
            async16(Bg0 + kb, Bw + dst0);
            async16(Bg1 + kb, Bw + dst0 + 1024);
        }
        __builtin_amdgcn_sched_barrier(0);

        const char* As = lds + c0;
        const char* Bs = As + 8192;
        bf16x8 a[4], b[4];
        #pragma unroll
        for (int i = 0; i < 4; ++i)
            a[i] = *(const bf16x8*)(As + (wm * 64 + i * 16 + l16) * 64 + xg);
        #pragma unroll
        for (int j = 0; j < 4; ++j)
            b[j] = *(const bf16x8*)(Bs + (wn * 64 + j * 16 + l16) * 64 + xg);
        #pragma unroll
        for (int i = 0; i < 4; ++i)
            #pragma unroll
            for (int j = 0; j < 4; ++j)
                acc[i][j] = __builtin_amdgcn_mfma_f32_16x16x32_bf16(a[i], b[j], acc[i][j], 0, 0, 0);

        c0 += 16384; if (c0 == 49152) c0 = 0;
        cr += 16384; if (cr == 49152) cr = 0;
    }
}

// ---------------------------------------------------------------------------
// Projections (q pre-scaled by 0.125*log2e), reading f32 Q/K/V directly.
// XCD-affinity 1D grid (1536) retained from round 3.
// ---------------------------------------------------------------------------
__global__ __launch_bounds__(256) void proj_gemm(
    const float* __restrict__ Qf, const float* __restrict__ Kf, const float* __restrict__ Vf,
    const short* __restrict__ wqT, const short* __restrict__ wkT, const short* __restrict__ wvT,
    const float* __restrict__ bq, const float* __restrict__ bk, const float* __restrict__ bv,
    short* __restrict__ qbuf, short* __restrict__ kbuf, short* __restrict__ vTbuf)
{
    __shared__ char lds[49152];
    int id = blockIdx.x;
    int xcd = id & 7;
    int k = id >> 3;                 // 0..191
    int which = k >> 6;              // 0..2
    int rem = k & 63;
    int r = ((rem >> 3) << 3) | xcd; // row-tile 0..63, row%8 == xcd
    int c = rem & 7;                 // col-tile 0..7

    const float* A  = (which == 0) ? Qf : (which == 1) ? Kf : Vf;
    const short* BT = (which == 0) ? wqT : (which == 1) ? wkT : wvT;
    const float* bias = (which == 0) ? bq : (which == 1) ? bk : bv;

    int rowM0 = r * 128;
    int colN0 = c * 128;

    f32x4 acc[4][4];
    #pragma unroll
    for (int i = 0; i < 4; ++i)
        #pragma unroll
        for (int j = 0; j < 4; ++j) acc[i][j] = (f32x4){0.f, 0.f, 0.f, 0.f};

    gemm_mainloop_f32A(A, BT, rowM0, colN0, lds, acc);

    int lane = threadIdx.x & 63, w = threadIdx.x >> 6;
    int l16 = lane & 15, quad = lane >> 4;
    int wm = w >> 1, wn = w & 1;

    if (which == 2) {
        #pragma unroll
        for (int j = 0; j < 4; ++j) {
            int col = colN0 + wn * 64 + j * 16 + l16;
            int hh = col >> 6, dv = col & 63;
            float bs = bias[col];
            #pragma unroll
            for (int i = 0; i < 4; ++i) {
                int rowb = rowM0 + wm * 64 + i * 16 + quad * 4;
                int bb = rowb >> 11, n0 = rowb & 2047;
                s16x4 pk;
                #pragma unroll
                for (int r2 = 0; r2 < 4; ++r2) pk[r2] = f2bs(acc[i][j][r2] + bs);
                *(s16x4*)(vTbuf + (((size_t)bb * H + hh) * DK + dv) * N_ + n0) = pk;
            }
        }
    } else {
        short* dst = (which == 0) ? qbuf : kbuf;
        float scl = (which == 0) ? 0.180336880f : 1.0f;   // 0.125 * log2(e)
        #pragma unroll
        for (int j = 0; j < 4; ++j) {
            int col = colN0 + wn * 64 + j * 16 + l16;
            float bs = bias[col];
            #pragma unroll
            for (int i = 0; i < 4; ++i) {
                int rowb = rowM0 + wm * 64 + i * 16 + quad * 4;
                #pragma unroll
                for (int r2 = 0; r2 < 4; ++r2)
                    dst[(size_t)(rowb + r2) * 1024 + col] = f2bs((acc[i][j][r2] + bs) * scl);
            }
        }
    }
}

// ---------------------------------------------------------------------------
// Output projection (XCD-affinity 1D grid, 512 blocks) — unchanged
// ---------------------------------------------------------------------------
__global__ __launch_bounds__(256) void out_gemm(
    const short* __restrict__ obuf, const short* __restrict__ woT,
    const float* __restrict__ bo, float* __restrict__ out)
{
    __shared__ char lds[49152];
    int id = blockIdx.x;
    int xcd = id & 7;
    int k = id >> 3;                 // 0..63
    int r = ((k >> 3) << 3) | xcd;   // row-tile 0..63
    int c = k & 7;                   // col-tile 0..7

    int rowM0 = r * 128;
    int colN0 = c * 128;

    f32x4 acc[4][4];
    #pragma unroll
    for (int i = 0; i < 4; ++i)
        #pragma unroll
        for (int j = 0; j < 4; ++j) acc[i][j] = (f32x4){0.f, 0.f, 0.f, 0.f};

    gemm_mainloop(obuf, woT, rowM0, colN0, lds, acc);

    int lane = threadIdx.x & 63, w = threadIdx.x >> 6;
    int l16 = lane & 15, quad = lane >> 4;
    int wm = w >> 1, wn = w & 1;

    #pragma unroll
    for (int j = 0; j < 4; ++j) {
        int col = colN0 + wn * 64 + j * 16 + l16;
        float bs = bo[col];
        #pragma unroll
        for (int i = 0; i < 4; ++i) {
            int rowb = rowM0 + wm * 64 + i * 16 + quad * 4;
            #pragma unroll
            for (int r2 = 0; r2 < 4; ++r2)
                out[(size_t)(rowb + r2) * 1024 + col] = acc[i][j][r2] + bs;
        }
    }
}

// ---------------------------------------------------------------------------
// Flash attention — unchanged (setprio around QK^T and PV MFMA clusters).
// ---------------------------------------------------------------------------
__global__ __launch_bounds__(256) void flash_kernel(
    const short* __restrict__ qbuf, const short* __restrict__ kbuf, const short* __restrict__ vT,
    short* __restrict__ obuf, const int* __restrict__ amask)
{
    __shared__ short Ks[2][4096];        // [key(perm)][dk] swizzled, dbuf
    __shared__ short Vs[2][4096];        // [dv][key] swizzled, dbuf
    __shared__ char  plds[4][2048];      // per-wave P tile 16x64, XOR-swizzled

    int bid = blockIdx.x;
    int g = bid & 7, idx = bid >> 3;
    int bh = g * 8 + (idx >> 4);         // XCD-affinity: one XCD -> 8 bh
    int xq = idx & 15;                   // q-tile pair selector
    int b = bh >> 4, h = bh & 15;

    int tid = threadIdx.x;
    int lane = tid & 63, wave = tid >> 6;
    int l16 = lane & 15, quad = lane >> 4;
    int msk = amask[0];

    int i8 = lane >> 3, i7 = lane & 7;
    int sg = (i7 ^ i8) << 4;
    int pk0 = i8 * 4 + wave;             // permuted K source row for LDS row wave*16+i8
    int skey = wave * 16 + i8;           // V source row (natural)
    int ldst = wave * 2048 + lane * 16;

    const char* kbase = (const char*)(kbuf + (size_t)b * 2048 * 1024 + h * 64);
    const char* vbase = (const char*)(vT + ((size_t)(b * 16 + h) * 64) * 2048);

    int m7 = l16 & 7;
    int g0 = (quad ^ m7) << 4;           // Ks/Vs read slots (row == l16 mod 8)
    int g1 = ((4 | quad) ^ m7) << 4;

    char* pw = plds[wave];
    int prd0 = l16 * 128 + g0;           // P A-frag reads (row = l16)
    int prd1 = l16 * 128 + g1;
    int pwa[4];                          // P write addrs (loop-invariant)
    #pragma unroll
    for (int r = 0; r < 4; ++r) {
        int row = quad * 4 + r;
        pwa[r] = row * 128 + (((l16 >> 1) ^ (row & 7)) << 4) + ((l16 & 1) << 3);
    }

    for (int pass = 0; pass < 2; ++pass) {
        int qt = pass ? (31 - xq) : xq;
        int qw = qt * 64 + wave * 16;
        int nkb = msk ? (qt + 1) : 32;

        const short* qp = qbuf + ((size_t)(b * 2048 + qw + l16)) * 1024 + h * 64;
        bf16x8 aq0 = *(const bf16x8*)(qp + quad * 8);
        bf16x8 aq1 = *(const bf16x8*)(qp + 32 + quad * 8);

        f32x4 o[4];
        float lsum[4];
        #pragma unroll
        for (int i = 0; i < 4; ++i) { o[i] = (f32x4){0.f, 0.f, 0.f, 0.f}; lsum[i] = 0.f; }

        // stage tile 0 into buffer 0
        async16(kbase + (size_t)pk0 * 2048 + sg, (char*)Ks[0] + ldst);
        async16(kbase + (size_t)(pk0 + 32) * 2048 + sg, (char*)Ks[0] + ldst + 1024);
        async16(vbase + (size_t)skey * 4096 + sg, (char*)Vs[0] + ldst);
        async16(vbase + (size_t)(skey + 8) * 4096 + sg, (char*)Vs[0] + ldst + 1024);

        for (int ib = 0; ib < nkb; ++ib) {
            __syncthreads();             // publishes buf[ib&1]
            int cur = ib & 1;
            if (ib + 1 < nkb) {
                int nb = (ib + 1) & 1;
                size_t kb2 = (size_t)(ib + 1) * 64;
                async16(kbase + (kb2 + pk0) * 2048 + sg, (char*)Ks[nb] + ldst);
                async16(kbase + (kb2 + pk0 + 32) * 2048 + sg, (char*)Ks[nb] + ldst + 1024);
                async16(vbase + (size_t)skey * 4096 + kb2 * 2 + sg, (char*)Vs[nb] + ldst);
                async16(vbase + (size_t)(skey + 8) * 4096 + kb2 * 2 + sg, (char*)Vs[nb] + ldst + 1024);
            }
            int kb = ib * 64;

            // S = q K^T (log2 domain; S column (nt,l16) = key 4*l16+nt)
            f32x4 s[4];
            __builtin_amdgcn_s_setprio(1);
            #pragma unroll
            for (int nt = 0; nt < 4; ++nt) {
                const char* kr = (const char*)Ks[cur] + (nt * 16 + l16) * 128;
                bf16x8 b0 = *(const bf16x8*)(kr + g0);
                bf16x8 b1 = *(const bf16x8*)(kr + g1);
                f32x4 t = (f32x4){0.f, 0.f, 0.f, 0.f};
                t = __builtin_amdgcn_mfma_f32_16x16x32_bf16(aq0, b0, t, 0, 0, 0);
                t = __builtin_amdgcn_mfma_f32_16x16x32_bf16(aq1, b1, t, 0, 0, 0);
                s[nt] = t;
            }
            __builtin_amdgcn_s_setprio(0);

            if (msk && (kb + 63 > qw)) {
                #pragma unroll
                for (int r = 0; r < 4; ++r) {
                    int row = qw + quad * 4 + r;
                    #pragma unroll
                    for (int nt = 0; nt < 4; ++nt) {
                        int col = kb + l16 * 4 + nt;
                        if (col > row) s[nt][r] = -3e38f;
                    }
                }
            }

            // p = exp2(s); truncation-pack to bf16 via v_perm; defer row sums
            __builtin_amdgcn_wave_barrier();
            #pragma unroll
            for (int r = 0; r < 4; ++r) {
                float p0 = __builtin_amdgcn_exp2f(s[0][r]);
                float p1 = __builtin_amdgcn_exp2f(s[1][r]);
                float p2 = __builtin_amdgcn_exp2f(s[2][r]);
                float p3 = __builtin_amdgcn_exp2f(s[3][r]);
                lsum[r] += (p0 + p1) + (p2 + p3);
                u32x2 pk;
                pk[0] = packbf(p0, p1);
                pk[1] = packbf(p2, p3);
                *(u32x2*)(pw + pwa[r]) = pk;
            }
            __builtin_amdgcn_wave_barrier();
            bf16x8 ap0 = *(const bf16x8*)(pw + prd0);
            bf16x8 ap1 = *(const bf16x8*)(pw + prd1);
            __builtin_amdgcn_wave_barrier();

            // O += P V (natural key order on both sides)
            __builtin_amdgcn_s_setprio(1);
            #pragma unroll
            for (int vb = 0; vb < 4; ++vb) {
                const char* vr = (const char*)Vs[cur] + (vb * 16 + l16) * 128;
                bf16x8 v0 = *(const bf16x8*)(vr + g0);
                bf16x8 v1 = *(const bf16x8*)(vr + g1);
                o[vb] = __builtin_amdgcn_mfma_f32_16x16x32_bf16(ap0, v0, o[vb], 0, 0, 0);
                o[vb] = __builtin_amdgcn_mfma_f32_16x16x32_bf16(ap1, v1, o[vb], 0, 0, 0);
            }
            __builtin_amdgcn_s_setprio(0);
        }

        // epilogue: reduce row sums across 16 col-lanes, normalize, store
        #pragma unroll
        for (int r = 0; r < 4; ++r) {
            float t = lsum[r];
            #pragma unroll
            for (int off = 1; off < 16; off <<= 1) t += __shfl_xor(t, off, 64);
            float inv = 1.0f / t;
            int row = qw + quad * 4 + r;
            #pragma unroll
            for (int vb = 0; vb < 4; ++vb)
                obuf[((size_t)(b * 2048 + row)) * 1024 + h * 64 + vb * 16 + l16] =
                    f2bs(o[vb][r] * inv);
        }
        __syncthreads();   // pass boundary: K/V buffers safe to restage
    }
}

// ---------------------------------------------------------------------------
extern "C" void kernel_launch(void* const* d_in, const int* in_sizes, int n_in,
                              void* d_out, int out_size, void* d_ws, size_t ws_size,
                              hipStream_t stream)
{
    const float* Q  = (const float*)d_in[0];
    const float* K  = (const float*)d_in[1];
    const float* V  = (const float*)d_in[2];
    const float* Wq = (const float*)d_in[3];
    const float* bq = (const float*)d_in[4];
    const float* Wk = (const float*)d_in[5];
    const float* bk = (const float*)d_in[6];
    const float* Wv = (const float*)d_in[7];
    const float* bv = (const float*)d_in[8];
    const float* Wo = (const float*)d_in[9];
    const float* bo = (const float*)d_in[10];
    const int* amask = (const int*)d_in[11];
    float* out = (float*)d_out;

    char* ws = (char*)d_ws;
    const size_t SZ = (size_t)B_ * N_ * DM * sizeof(short);      // 16 MiB each
    const size_t SZW = (size_t)H * DK * DM * sizeof(short);      // 2 MiB each
    short* obuf  = (short*)ws; ws += SZ;
    short* qbuf  = (short*)ws; ws += SZ;
    short* kbuf  = (short*)ws; ws += SZ;
    short* vTbuf = (short*)ws; ws += SZ;
    short* wqT   = (short*)ws; ws += SZW;
    short* wkT   = (short*)ws; ws += SZW;
    short* wvT   = (short*)ws; ws += SZW;
    short* woT   = (short*)ws; ws += SZW;

    prep_w<<<dim3(1024), dim3(256), 0, stream>>>(Wq, Wk, Wv, Wo, wqT, wkT, wvT, woT);
    proj_gemm<<<dim3(1536), dim3(256), 0, stream>>>(Q, K, V, wqT, wkT, wvT,
                                                    bq, bk, bv, qbuf, kbuf, vTbuf);
    flash_kernel<<<dim3(1024), dim3(256), 0, stream>>>(qbuf, kbuf, vTbuf, obuf, amask);
    out_gemm<<<dim3(512), dim3(256), 0, stream>>>(obuf, woT, bo, out);
}

// Round 5
// 327.986 us; speedup vs baseline: 1.0231x; 1.0231x over previous
//
#include <hip/hip_runtime.h>
#include <hip/hip_bf16.h>

#define H 16
#define DM 1024
#define DK 64
#define B_ 4
#define N_ 2048

typedef __attribute__((ext_vector_type(8))) short bf16x8;
typedef __attribute__((ext_vector_type(4))) short s16x4;
typedef __attribute__((ext_vector_type(2))) unsigned int u32x2;
typedef __attribute__((ext_vector_type(4))) float f32x4;

static __device__ __forceinline__ short f2bs(float x) {
    __hip_bfloat16 b = __float2bfloat16(x);
    return *reinterpret_cast<short*>(&b);
}

// async 16B global -> LDS (LDS side is wave base + lane*16)
static __device__ __forceinline__ void async16(const void* g, void* l) {
    __builtin_amdgcn_global_load_lds(
        (const __attribute__((address_space(1))) void*)g,
        (__attribute__((address_space(3))) void*)l, 16, 0, 0);
}

// pack two fp32 -> two bf16 (truncation) in one v_perm_b32
static __device__ __forceinline__ unsigned packbf(float lo, float hi) {
    return __builtin_amdgcn_perm(__float_as_uint(hi), __float_as_uint(lo), 0x07060302u);
}

// ---------------------------------------------------------------------------
// Prep: y<3 -> fp32->bf16 convert of Q/K/V; y==3,x<1024 -> weight transposes
// (restored: separate prep is cheaper than polluting the GEMM load stream —
//  round-4 fusion regressed proj 75->133 us)
// ---------------------------------------------------------------------------
__global__ __launch_bounds__(256) void prep_kernel(
    const float* __restrict__ Q, const float* __restrict__ K, const float* __restrict__ V,
    const float* __restrict__ Wq, const float* __restrict__ Wk,
    const float* __restrict__ Wv, const float* __restrict__ Wo,
    short* __restrict__ Qb, short* __restrict__ Kb, short* __restrict__ Vb,
    short* __restrict__ wqT, short* __restrict__ wkT,
    short* __restrict__ wvT, short* __restrict__ woT)
{
    int y = blockIdx.y;
    if (y < 3) {
        const float* s = (y == 0) ? Q : (y == 1) ? K : V;
        short* d = (y == 0) ? Qb : (y == 1) ? Kb : Vb;
        size_t i = ((size_t)blockIdx.x * 256 + threadIdx.x) * 8;
        f32x4 a = *(const f32x4*)(s + i);
        f32x4 b = *(const f32x4*)(s + i + 4);
        bf16x8 p;
        #pragma unroll
        for (int j = 0; j < 4; ++j) { p[j] = f2bs(a[j]); p[4 + j] = f2bs(b[j]); }
        *(bf16x8*)(d + i) = p;
        return;
    }
    if (blockIdx.x >= 1024) return;
    __shared__ float tile[64][65];
    int z = blockIdx.x >> 8;
    int bx = blockIdx.x & 255;
    int t = threadIdx.x;
    int tj = t & 63, ti = t >> 6;

    if (z < 3) {
        const float* src = (z == 0) ? Wq : (z == 1) ? Wk : Wv;
        short* dst = (z == 0) ? wqT : (z == 1) ? wkT : wvT;
        int h = bx >> 4;
        int dmt = bx & 15;
        #pragma unroll
        for (int r = 0; r < 16; ++r) {
            int i = r * 4 + ti;
            tile[i][tj] = src[((size_t)h * 1024 + dmt * 64 + i) * 64 + tj];
        }
        __syncthreads();
        #pragma unroll
        for (int r = 0; r < 16; ++r) {
            int dk = r * 4 + ti;
            dst[((size_t)h * 64 + dk) * 1024 + dmt * 64 + tj] = f2bs(tile[tj][dk]);
        }
    } else {
        int kt = bx >> 4;
        int nt = bx & 15;
        #pragma unroll
        for (int r = 0; r < 16; ++r) {
            int i = r * 4 + ti;
            tile[i][tj] = Wo[((size_t)kt * 64 + i) * 1024 + nt * 64 + tj];
        }
        __syncthreads();
        #pragma unroll
        for (int r = 0; r < 16; ++r) {
            int jn = r * 4 + ti;
            woT[((size_t)nt * 64 + jn) * 1024 + kt * 64 + tj] = f2bs(tile[tj][jn]);
        }
    }
}

// ---------------------------------------------------------------------------
// GEMM mainloop: counted-vmcnt pipeline, ONE barrier per K-step (round 3).
// 3 x 16KB rotating LDS bufs; steady-state wait vmcnt(4), never 0 (T4).
// Tile 128x128, BK=32, 4 waves as 2x2 of 64x64.
// ---------------------------------------------------------------------------
static __device__ __forceinline__ void gemm_mainloop(
    const short* __restrict__ A, const short* __restrict__ BT,
    int rowM0, int colN0, char* lds, f32x4 (&acc)[4][4])
{
    int tid = threadIdx.x;
    int lane = tid & 63, w = tid >> 6;
    int l16 = lane & 15, quad = lane >> 4;
    int wm = w >> 1, wn = w & 1;
    int xg = (quad ^ ((l16 >> 1) & 3)) << 4;   // swizzled read slot

    int r0 = w * 32 + (lane >> 2);
    int gsl = ((lane & 3) ^ ((lane >> 3) & 3)) << 4;
    int dst0 = w * 2048 + lane * 16;
    const char* Ag0 = (const char*)A + (size_t)(rowM0 + r0) * 2048 + gsl;
    const char* Ag1 = Ag0 + 16 * 2048;
    const char* Bg0 = (const char*)BT + (size_t)(colN0 + r0) * 2048 + gsl;
    const char* Bg1 = Bg0 + 16 * 2048;

    #pragma unroll
    for (int t = 0; t < 2; ++t) {
        size_t kb = (size_t)t * 64;
        char* As = lds + t * 16384;
        char* Bs = As + 8192;
        async16(Ag0 + kb, As + dst0);
        async16(Ag1 + kb, As + dst0 + 1024);
        async16(Bg0 + kb, Bs + dst0);
        async16(Bg1 + kb, Bs + dst0 + 1024);
    }

    int c0 = 0;
    int cr = 32768;
    for (int it = 0; it < 32; ++it) {
        if (it < 31) asm volatile("s_waitcnt vmcnt(4)" ::: "memory");
        else         asm volatile("s_waitcnt vmcnt(0)" ::: "memory");
        __builtin_amdgcn_s_barrier();
        __builtin_amdgcn_sched_barrier(0);

        if (it + 2 < 32) {
            size_t kb = (size_t)(it + 2) * 64;
            char* Aw = lds + cr;
            char* Bw = Aw + 8192;
            async16(Ag0 + kb, Aw + dst0);
            async16(Ag1 + kb, Aw + dst0 + 1024);
            async16(Bg0 + kb, Bw + dst0);
            async16(Bg1 + kb, Bw + dst0 + 1024);
        }
        __builtin_amdgcn_sched_barrier(0);

        const char* As = lds + c0;
        const char* Bs = As + 8192;
        bf16x8 a[4], b[4];
        #pragma unroll
        for (int i = 0; i < 4; ++i)
            a[i] = *(const bf16x8*)(As + (wm * 64 + i * 16 + l16) * 64 + xg);
        #pragma unroll
        for (int j = 0; j < 4; ++j)
            b[j] = *(const bf16x8*)(Bs + (wn * 64 + j * 16 + l16) * 64 + xg);
        #pragma unroll
        for (int i = 0; i < 4; ++i)
            #pragma unroll
            for (int j = 0; j < 4; ++j)
                acc[i][j] = __builtin_amdgcn_mfma_f32_16x16x32_bf16(a[i], b[j], acc[i][j], 0, 0, 0);

        c0 += 16384; if (c0 == 49152) c0 = 0;
        cr += 16384; if (cr == 49152) cr = 0;
    }
}

// ---------------------------------------------------------------------------
// Projections (q pre-scaled by 0.125*log2e). Linear grid (64,8,3) — the
// round-3 XCD swizzle cost proj ~3us; reverted.
// ---------------------------------------------------------------------------
__global__ __launch_bounds__(256) void proj_gemm(
    const short* __restrict__ Qb, const short* __restrict__ Kb, const short* __restrict__ Vb,
    const short* __restrict__ wqT, const short* __restrict__ wkT, const short* __restrict__ wvT,
    const float* __restrict__ bq, const float* __restrict__ bk, const float* __restrict__ bv,
    short* __restrict__ qbuf, short* __restrict__ kbuf, short* __restrict__ vTbuf)
{
    __shared__ char lds[49152];
    int which = blockIdx.z;
    const short* A  = (which == 0) ? Qb : (which == 1) ? Kb : Vb;
    const short* BT = (which == 0) ? wqT : (which == 1) ? wkT : wvT;
    const float* bias = (which == 0) ? bq : (which == 1) ? bk : bv;

    int rowM0 = blockIdx.x * 128;
    int colN0 = blockIdx.y * 128;

    f32x4 acc[4][4];
    #pragma unroll
    for (int i = 0; i < 4; ++i)
        #pragma unroll
        for (int j = 0; j < 4; ++j) acc[i][j] = (f32x4){0.f, 0.f, 0.f, 0.f};

    gemm_mainloop(A, BT, rowM0, colN0, lds, acc);

    int lane = threadIdx.x & 63, w = threadIdx.x >> 6;
    int l16 = lane & 15, quad = lane >> 4;
    int wm = w >> 1, wn = w & 1;

    if (which == 2) {
        #pragma unroll
        for (int j = 0; j < 4; ++j) {
            int col = colN0 + wn * 64 + j * 16 + l16;
            int hh = col >> 6, dv = col & 63;
            float bs = bias[col];
            #pragma unroll
            for (int i = 0; i < 4; ++i) {
                int rowb = rowM0 + wm * 64 + i * 16 + quad * 4;
                int bb = rowb >> 11, n0 = rowb & 2047;
                s16x4 pk;
                #pragma unroll
                for (int r2 = 0; r2 < 4; ++r2) pk[r2] = f2bs(acc[i][j][r2] + bs);
                *(s16x4*)(vTbuf + (((size_t)bb * H + hh) * DK + dv) * N_ + n0) = pk;
            }
        }
    } else {
        short* dst = (which == 0) ? qbuf : kbuf;
        float scl = (which == 0) ? 0.180336880f : 1.0f;   // 0.125 * log2(e)
        #pragma unroll
        for (int j = 0; j < 4; ++j) {
            int col = colN0 + wn * 64 + j * 16 + l16;
            float bs = bias[col];
            #pragma unroll
            for (int i = 0; i < 4; ++i) {
                int rowb = rowM0 + wm * 64 + i * 16 + quad * 4;
                #pragma unroll
                for (int r2 = 0; r2 < 4; ++r2)
                    dst[(size_t)(rowb + r2) * 1024 + col] = f2bs((acc[i][j][r2] + bs) * scl);
            }
        }
    }
}

// ---------------------------------------------------------------------------
// Output projection (linear grid 64x8)
// ---------------------------------------------------------------------------
__global__ __launch_bounds__(256) void out_gemm(
    const short* __restrict__ obuf, const short* __restrict__ woT,
    const float* __restrict__ bo, float* __restrict__ out)
{
    __shared__ char lds[49152];
    int rowM0 = blockIdx.x * 128;
    int colN0 = blockIdx.y * 128;

    f32x4 acc[4][4];
    #pragma unroll
    for (int i = 0; i < 4; ++i)
        #pragma unroll
        for (int j = 0; j < 4; ++j) acc[i][j] = (f32x4){0.f, 0.f, 0.f, 0.f};

    gemm_mainloop(obuf, woT, rowM0, colN0, lds, acc);

    int lane = threadIdx.x & 63, w = threadIdx.x >> 6;
    int l16 = lane & 15, quad = lane >> 4;
    int wm = w >> 1, wn = w & 1;

    #pragma unroll
    for (int j = 0; j < 4; ++j) {
        int col = colN0 + wn * 64 + j * 16 + l16;
        float bs = bo[col];
        #pragma unroll
        for (int i = 0; i < 4; ++i) {
            int rowb = rowM0 + wm * 64 + i * 16 + quad * 4;
            #pragma unroll
            for (int r2 = 0; r2 < 4; ++r2)
                out[(size_t)(rowb + r2) * 1024 + col] = acc[i][j][r2] + bs;
        }
    }
}

// ---------------------------------------------------------------------------
// Flash attention (round 9): MERGED passes. Each block handles q-tiles
// qtA = xq (small) and qtB = 31-xq (large) in ONE K-loop, staging each K/V
// tile ONCE (was: two passes, 33 stagings + 35 barriers). Staging drops to
// 32-xq tiles (avg 24.5, -26%); during the overlap region each staged tile
// feeds both q-tiles' MFMA work. Compute stays balanced at 33 q-tile-steps
// per block. Per-wave P LDS buffer is time-shared (in-order per-wave LDS).
// ---------------------------------------------------------------------------
__global__ __launch_bounds__(256) void flash_kernel(
    const short* __restrict__ qbuf, const short* __restrict__ kbuf, const short* __restrict__ vT,
    short* __restrict__ obuf, const int* __restrict__ amask)
{
    __shared__ short Ks[2][4096];        // [key(perm)][dk] swizzled, dbuf
    __shared__ short Vs[2][4096];        // [dv][key] swizzled, dbuf
    __shared__ char  plds[4][2048];      // per-wave P tile 16x64, XOR-swizzled

    int bid = blockIdx.x;
    int g = bid & 7, idx = bid >> 3;
    int bh = g * 8 + (idx >> 4);         // XCD-affinity: one XCD -> 8 bh
    int xq = idx & 15;                   // q-tile pair selector
    int b = bh >> 4, h = bh & 15;

    int tid = threadIdx.x;
    int lane = tid & 63, wave = tid >> 6;
    int l16 = lane & 15, quad = lane >> 4;
    int msk = amask[0];

    int i8 = lane >> 3, i7 = lane & 7;
    int sg = (i7 ^ i8) << 4;
    int pk0 = i8 * 4 + wave;             // permuted K source row for LDS row wave*16+i8
    int skey = wave * 16 + i8;           // V source row (natural)
    int ldst = wave * 2048 + lane * 16;

    const char* kbase = (const char*)(kbuf + (size_t)b * 2048 * 1024 + h * 64);
    const char* vbase = (const char*)(vT + ((size_t)(b * 16 + h) * 64) * 2048);

    int m7 = l16 & 7;
    int g0 = (quad ^ m7) << 4;           // Ks/Vs read slots (row == l16 mod 8)
    int g1 = ((4 | quad) ^ m7) << 4;

    char* pw = plds[wave];
    int prd0 = l16 * 128 + g0;           // P A-frag reads (row = l16)
    int prd1 = l16 * 128 + g1;
    int pwa[4];                          // P write addrs (loop-invariant)
    #pragma unroll
    for (int r = 0; r < 4; ++r) {
        int row = quad * 4 + r;
        pwa[r] = row * 128 + (((l16 >> 1) ^ (row & 7)) << 4) + ((l16 & 1) << 3);
    }

    int qtA = xq, qtB = 31 - xq;
    int qwA = qtA * 64 + wave * 16;
    int qwB = qtB * 64 + wave * 16;
    int nkbA = msk ? (qtA + 1) : 32;
    int nkbB = msk ? (qtB + 1) : 32;     // nkbB >= nkbA always

    const short* qpA = qbuf + ((size_t)(b * 2048 + qwA + l16)) * 1024 + h * 64;
    const short* qpB = qbuf + ((size_t)(b * 2048 + qwB + l16)) * 1024 + h * 64;
    bf16x8 aqA0 = *(const bf16x8*)(qpA + quad * 8);
    bf16x8 aqA1 = *(const bf16x8*)(qpA + 32 + quad * 8);
    bf16x8 aqB0 = *(const bf16x8*)(qpB + quad * 8);
    bf16x8 aqB1 = *(const bf16x8*)(qpB + 32 + quad * 8);

    f32x4 oA[4], oB[4];
    float lsA[4], lsB[4];
    #pragma unroll
    for (int i = 0; i < 4; ++i) {
        oA[i] = (f32x4){0.f, 0.f, 0.f, 0.f};
        oB[i] = (f32x4){0.f, 0.f, 0.f, 0.f};
        lsA[i] = 0.f; lsB[i] = 0.f;
    }

    // stage tile 0 into buffer 0
    async16(kbase + (size_t)pk0 * 2048 + sg, (char*)Ks[0] + ldst);
    async16(kbase + (size_t)(pk0 + 32) * 2048 + sg, (char*)Ks[0] + ldst + 1024);
    async16(vbase + (size_t)skey * 4096 + sg, (char*)Vs[0] + ldst);
    async16(vbase + (size_t)(skey + 8) * 4096 + sg, (char*)Vs[0] + ldst + 1024);

    for (int ib = 0; ib < nkbB; ++ib) {
        __syncthreads();             // publishes buf[ib&1]
        int cur = ib & 1;
        if (ib + 1 < nkbB) {
            int nb = (ib + 1) & 1;
            size_t kb2 = (size_t)(ib + 1) * 64;
            async16(kbase + (kb2 + pk0) * 2048 + sg, (char*)Ks[nb] + ldst);
            async16(kbase + (kb2 + pk0 + 32) * 2048 + sg, (char*)Ks[nb] + ldst + 1024);
            async16(vbase + (size_t)skey * 4096 + kb2 * 2 + sg, (char*)Vs[nb] + ldst);
            async16(vbase + (size_t)(skey + 8) * 4096 + kb2 * 2 + sg, (char*)Vs[nb] + ldst + 1024);
        }
        int kb = ib * 64;

        // =============== q-tile B (always active) ===============
        {
            f32x4 s[4];
            __builtin_amdgcn_s_setprio(1);
            #pragma unroll
            for (int nt = 0; nt < 4; ++nt) {
                const char* kr = (const char*)Ks[cur] + (nt * 16 + l16) * 128;
                bf16x8 b0 = *(const bf16x8*)(kr + g0);
                bf16x8 b1 = *(const bf16x8*)(kr + g1);
                f32x4 t = (f32x4){0.f, 0.f, 0.f, 0.f};
                t = __builtin_amdgcn_mfma_f32_16x16x32_bf16(aqB0, b0, t, 0, 0, 0);
                t = __builtin_amdgcn_mfma_f32_16x16x32_bf16(aqB1, b1, t, 0, 0, 0);
                s[nt] = t;
            }
            __builtin_amdgcn_s_setprio(0);

            if (msk && (kb + 63 > qwB)) {
                #pragma unroll
                for (int r = 0; r < 4; ++r) {
                    int row = qwB + quad * 4 + r;
                    #pragma unroll
                    for (int nt = 0; nt < 4; ++nt) {
                        int col = kb + l16 * 4 + nt;
                        if (col > row) s[nt][r] = -3e38f;
                    }
                }
            }

            __builtin_amdgcn_wave_barrier();
            #pragma unroll
            for (int r = 0; r < 4; ++r) {
                float p0 = __builtin_amdgcn_exp2f(s[0][r]);
                float p1 = __builtin_amdgcn_exp2f(s[1][r]);
                float p2 = __builtin_amdgcn_exp2f(s[2][r]);
                float p3 = __builtin_amdgcn_exp2f(s[3][r]);
                lsB[r] += (p0 + p1) + (p2 + p3);
                u32x2 pk;
                pk[0] = packbf(p0, p1);
                pk[1] = packbf(p2, p3);
                *(u32x2*)(pw + pwa[r]) = pk;
            }
            __builtin_amdgcn_wave_barrier();
            bf16x8 ap0 = *(const bf16x8*)(pw + prd0);
            bf16x8 ap1 = *(const bf16x8*)(pw + prd1);
            __builtin_amdgcn_wave_barrier();

            __builtin_amdgcn_s_setprio(1);
            #pragma unroll
            for (int vb = 0; vb < 4; ++vb) {
                const char* vr = (const char*)Vs[cur] + (vb * 16 + l16) * 128;
                bf16x8 v0 = *(const bf16x8*)(vr + g0);
                bf16x8 v1 = *(const bf16x8*)(vr + g1);
                oB[vb] = __builtin_amdgcn_mfma_f32_16x16x32_bf16(ap0, v0, oB[vb], 0, 0, 0);
                oB[vb] = __builtin_amdgcn_mfma_f32_16x16x32_bf16(ap1, v1, oB[vb], 0, 0, 0);
            }
            __builtin_amdgcn_s_setprio(0);
        }

        // =============== q-tile A (active while ib < nkbA) ===============
        if (ib < nkbA) {
            f32x4 s[4];
            __builtin_amdgcn_s_setprio(1);
            #pragma unroll
            for (int nt = 0; nt < 4; ++nt) {
                const char* kr = (const char*)Ks[cur] + (nt * 16 + l16) * 128;
                bf16x8 b0 = *(const bf16x8*)(kr + g0);
                bf16x8 b1 = *(const bf16x8*)(kr + g1);
                f32x4 t = (f32x4){0.f, 0.f, 0.f, 0.f};
                t = __builtin_amdgcn_mfma_f32_16x16x32_bf16(aqA0, b0, t, 0, 0, 0);
                t = __builtin_amdgcn_mfma_f32_16x16x32_bf16(aqA1, b1, t, 0, 0, 0);
                s[nt] = t;
            }
            __builtin_amdgcn_s_setprio(0);

            if (msk && (kb + 63 > qwA)) {
                #pragma unroll
                for (int r = 0; r < 4; ++r) {
                    int row = qwA + quad * 4 + r;
                    #pragma unroll
                    for (int nt = 0; nt < 4; ++nt) {
                        int col = kb + l16 * 4 + nt;
                        if (col > row) s[nt][r] = -3e38f;
                    }
                }
            }

            __builtin_amdgcn_wave_barrier();
            #pragma unroll
            for (int r = 0; r < 4; ++r) {
                float p0 = __builtin_amdgcn_exp2f(s[0][r]);
                float p1 = __builtin_amdgcn_exp2f(s[1][r]);
                float p2 = __builtin_amdgcn_exp2f(s[2][r]);
                float p3 = __builtin_amdgcn_exp2f(s[3][r]);
                lsA[r] += (p0 + p1) + (p2 + p3);
                u32x2 pk;
                pk[0] = packbf(p0, p1);
                pk[1] = packbf(p2, p3);
                *(u32x2*)(pw + pwa[r]) = pk;
            }
            __builtin_amdgcn_wave_barrier();
            bf16x8 ap0 = *(const bf16x8*)(pw + prd0);
            bf16x8 ap1 = *(const bf16x8*)(pw + prd1);
            __builtin_amdgcn_wave_barrier();

            __builtin_amdgcn_s_setprio(1);
            #pragma unroll
            for (int vb = 0; vb < 4; ++vb) {
                const char* vr = (const char*)Vs[cur] + (vb * 16 + l16) * 128;
                bf16x8 v0 = *(const bf16x8*)(vr + g0);
                bf16x8 v1 = *(const bf16x8*)(vr + g1);
                oA[vb] = __builtin_amdgcn_mfma_f32_16x16x32_bf16(ap0, v0, oA[vb], 0, 0, 0);
                oA[vb] = __builtin_amdgcn_mfma_f32_16x16x32_bf16(ap1, v1, oA[vb], 0, 0, 0);
            }
            __builtin_amdgcn_s_setprio(0);
        }
    }

    // epilogue: reduce row sums across 16 col-lanes, normalize, store (B then A)
    #pragma unroll
    for (int r = 0; r < 4; ++r) {
        float t = lsB[r];
        #pragma unroll
        for (int off = 1; off < 16; off <<= 1) t += __shfl_xor(t, off, 64);
        float inv = 1.0f / t;
        int row = qwB + quad * 4 + r;
        #pragma unroll
        for (int vb = 0; vb < 4; ++vb)
            obuf[((size_t)(b * 2048 + row)) * 1024 + h * 64 + vb * 16 + l16] =
                f2bs(oB[vb][r] * inv);
    }
    #pragma unroll
    for (int r = 0; r < 4; ++r) {
        float t = lsA[r];
        #pragma unroll
        for (int off = 1; off < 16; off <<= 1) t += __shfl_xor(t, off, 64);
        float inv = 1.0f / t;
        int row = qwA + quad * 4 + r;
        #pragma unroll
        for (int vb = 0; vb < 4; ++vb)
            obuf[((size_t)(b * 2048 + row)) * 1024 + h * 64 + vb * 16 + l16] =
                f2bs(oA[vb][r] * inv);
    }
}

// ---------------------------------------------------------------------------
extern "C" void kernel_launch(void* const* d_in, const int* in_sizes, int n_in,
                              void* d_out, int out_size, void* d_ws, size_t ws_size,
                              hipStream_t stream)
{
    const float* Q  = (const float*)d_in[0];
    const float* K  = (const float*)d_in[1];
    const float* V  = (const float*)d_in[2];
    const float* Wq = (const float*)d_in[3];
    const float* bq = (const float*)d_in[4];
    const float* Wk = (const float*)d_in[5];
    const float* bk = (const float*)d_in[6];
    const float* Wv = (const float*)d_in[7];
    const float* bv = (const float*)d_in[8];
    const float* Wo = (const float*)d_in[9];
    const float* bo = (const float*)d_in[10];
    const int* amask = (const int*)d_in[11];
    float* out = (float*)d_out;

    char* ws = (char*)d_ws;
    const size_t SZ = (size_t)B_ * N_ * DM * sizeof(short);      // 16 MiB each
    const size_t SZW = (size_t)H * DK * DM * sizeof(short);      // 2 MiB each
    short* Qb    = (short*)ws; ws += SZ;       // reused as obuf after proj
    short* Kb    = (short*)ws; ws += SZ;
    short* Vb    = (short*)ws; ws += SZ;
    short* qbuf  = (short*)ws; ws += SZ;
    short* kbuf  = (short*)ws; ws += SZ;
    short* vTbuf = (short*)ws; ws += SZ;
    short* wqT   = (short*)ws; ws += SZW;
    short* wkT   = (short*)ws; ws += SZW;
    short* wvT   = (short*)ws; ws += SZW;
    short* woT   = (short*)ws; ws += SZW;
    short* obuf  = Qb;

    prep_kernel<<<dim3(4096, 4), dim3(256), 0, stream>>>(Q, K, V, Wq, Wk, Wv, Wo,
                                                         Qb, Kb, Vb, wqT, wkT, wvT, woT);
    proj_gemm<<<dim3(64, 8, 3), dim3(256), 0, stream>>>(Qb, Kb, Vb, wqT, wkT, wvT,
                                                        bq, bk, bv, qbuf, kbuf, vTbuf);
    flash_kernel<<<dim3(1024), dim3(256), 0, stream>>>(qbuf, kbuf, vTbuf, obuf, amask);
    out_gemm<<<dim3(64, 8), dim3(256), 0, stream>>>(obuf, woT, bo, out);
}

// Round 6
// 314.638 us; speedup vs baseline: 1.0665x; 1.0424x over previous
//
#include <hip/hip_runtime.h>
#include <hip/hip_bf16.h>

#define H 16
#define DM 1024
#define DK 64
#define B_ 4
#define N_ 2048

typedef __attribute__((ext_vector_type(8))) short bf16x8;
typedef __attribute__((ext_vector_type(4))) short s16x4;
typedef __attribute__((ext_vector_type(2))) unsigned int u32x2;
typedef __attribute__((ext_vector_type(4))) float f32x4;

static __device__ __forceinline__ short f2bs(float x) {
    __hip_bfloat16 b = __float2bfloat16(x);
    return *reinterpret_cast<short*>(&b);
}

// async 16B global -> LDS (LDS side is wave base + lane*16)
static __device__ __forceinline__ void async16(const void* g, void* l) {
    __builtin_amdgcn_global_load_lds(
        (const __attribute__((address_space(1))) void*)g,
        (__attribute__((address_space(3))) void*)l, 16, 0, 0);
}

// pack two fp32 -> two bf16 (truncation) in one v_perm_b32
static __device__ __forceinline__ unsigned packbf(float lo, float hi) {
    return __builtin_amdgcn_perm(__float_as_uint(hi), __float_as_uint(lo), 0x07060302u);
}

// ---------------------------------------------------------------------------
// Prep: y<3 -> fp32->bf16 convert of Q/K/V; y==3,x<1024 -> weight transposes
// (separate prep is cheaper than polluting the GEMM load stream — round-4
//  fusion regressed proj 75->133 us)
// ---------------------------------------------------------------------------
__global__ __launch_bounds__(256) void prep_kernel(
    const float* __restrict__ Q, const float* __restrict__ K, const float* __restrict__ V,
    const float* __restrict__ Wq, const float* __restrict__ Wk,
    const float* __restrict__ Wv, const float* __restrict__ Wo,
    short* __restrict__ Qb, short* __restrict__ Kb, short* __restrict__ Vb,
    short* __restrict__ wqT, short* __restrict__ wkT,
    short* __restrict__ wvT, short* __restrict__ woT)
{
    int y = blockIdx.y;
    if (y < 3) {
        const float* s = (y == 0) ? Q : (y == 1) ? K : V;
        short* d = (y == 0) ? Qb : (y == 1) ? Kb : Vb;
        size_t i = ((size_t)blockIdx.x * 256 + threadIdx.x) * 8;
        f32x4 a = *(const f32x4*)(s + i);
        f32x4 b = *(const f32x4*)(s + i + 4);
        bf16x8 p;
        #pragma unroll
        for (int j = 0; j < 4; ++j) { p[j] = f2bs(a[j]); p[4 + j] = f2bs(b[j]); }
        *(bf16x8*)(d + i) = p;
        return;
    }
    if (blockIdx.x >= 1024) return;
    __shared__ float tile[64][65];
    int z = blockIdx.x >> 8;
    int bx = blockIdx.x & 255;
    int t = threadIdx.x;
    int tj = t & 63, ti = t >> 6;

    if (z < 3) {
        const float* src = (z == 0) ? Wq : (z == 1) ? Wk : Wv;
        short* dst = (z == 0) ? wqT : (z == 1) ? wkT : wvT;
        int h = bx >> 4;
        int dmt = bx & 15;
        #pragma unroll
        for (int r = 0; r < 16; ++r) {
            int i = r * 4 + ti;
            tile[i][tj] = src[((size_t)h * 1024 + dmt * 64 + i) * 64 + tj];
        }
        __syncthreads();
        #pragma unroll
        for (int r = 0; r < 16; ++r) {
            int dk = r * 4 + ti;
            dst[((size_t)h * 64 + dk) * 1024 + dmt * 64 + tj] = f2bs(tile[tj][dk]);
        }
    } else {
        int kt = bx >> 4;
        int nt = bx & 15;
        #pragma unroll
        for (int r = 0; r < 16; ++r) {
            int i = r * 4 + ti;
            tile[i][tj] = Wo[((size_t)kt * 64 + i) * 1024 + nt * 64 + tj];
        }
        __syncthreads();
        #pragma unroll
        for (int r = 0; r < 16; ++r) {
            int jn = r * 4 + ti;
            woT[((size_t)nt * 64 + jn) * 1024 + kt * 64 + tj] = f2bs(tile[tj][jn]);
        }
    }
}

// ---------------------------------------------------------------------------
// GEMM mainloop: counted-vmcnt pipeline, ONE barrier per K-step.
// 3 x 16KB rotating LDS bufs; steady-state wait vmcnt(4), never 0 (T4).
// Tile 128x128, BK=32, 4 waves as 2x2 of 64x64.
// ---------------------------------------------------------------------------
static __device__ __forceinline__ void gemm_mainloop(
    const short* __restrict__ A, const short* __restrict__ BT,
    int rowM0, int colN0, char* lds, f32x4 (&acc)[4][4])
{
    int tid = threadIdx.x;
    int lane = tid & 63, w = tid >> 6;
    int l16 = lane & 15, quad = lane >> 4;
    int wm = w >> 1, wn = w & 1;
    int xg = (quad ^ ((l16 >> 1) & 3)) << 4;   // swizzled read slot

    int r0 = w * 32 + (lane >> 2);
    int gsl = ((lane & 3) ^ ((lane >> 3) & 3)) << 4;
    int dst0 = w * 2048 + lane * 16;
    const char* Ag0 = (const char*)A + (size_t)(rowM0 + r0) * 2048 + gsl;
    const char* Ag1 = Ag0 + 16 * 2048;
    const char* Bg0 = (const char*)BT + (size_t)(colN0 + r0) * 2048 + gsl;
    const char* Bg1 = Bg0 + 16 * 2048;

    #pragma unroll
    for (int t = 0; t < 2; ++t) {
        size_t kb = (size_t)t * 64;
        char* As = lds + t * 16384;
        char* Bs = As + 8192;
        async16(Ag0 + kb, As + dst0);
        async16(Ag1 + kb, As + dst0 + 1024);
        async16(Bg0 + kb, Bs + dst0);
        async16(Bg1 + kb, Bs + dst0 + 1024);
    }

    int c0 = 0;
    int cr = 32768;
    for (int it = 0; it < 32; ++it) {
        if (it < 31) asm volatile("s_waitcnt vmcnt(4)" ::: "memory");
        else         asm volatile("s_waitcnt vmcnt(0)" ::: "memory");
        __builtin_amdgcn_s_barrier();
        __builtin_amdgcn_sched_barrier(0);

        if (it + 2 < 32) {
            size_t kb = (size_t)(it + 2) * 64;
            char* Aw = lds + cr;
            char* Bw = Aw + 8192;
            async16(Ag0 + kb, Aw + dst0);
            async16(Ag1 + kb, Aw + dst0 + 1024);
            async16(Bg0 + kb, Bw + dst0);
            async16(Bg1 + kb, Bw + dst0 + 1024);
        }
        __builtin_amdgcn_sched_barrier(0);

        const char* As = lds + c0;
        const char* Bs = As + 8192;
        bf16x8 a[4], b[4];
        #pragma unroll
        for (int i = 0; i < 4; ++i)
            a[i] = *(const bf16x8*)(As + (wm * 64 + i * 16 + l16) * 64 + xg);
        #pragma unroll
        for (int j = 0; j < 4; ++j)
            b[j] = *(const bf16x8*)(Bs + (wn * 64 + j * 16 + l16) * 64 + xg);
        #pragma unroll
        for (int i = 0; i < 4; ++i)
            #pragma unroll
            for (int j = 0; j < 4; ++j)
                acc[i][j] = __builtin_amdgcn_mfma_f32_16x16x32_bf16(a[i], b[j], acc[i][j], 0, 0, 0);

        c0 += 16384; if (c0 == 49152) c0 = 0;
        cr += 16384; if (cr == 49152) cr = 0;
    }
}

// ---------------------------------------------------------------------------
// Projections (q pre-scaled by 0.125*log2e). Linear grid (64,8,3) — the
// XCD swizzle cost proj ~3us (round 3); linear is best-known.
// ---------------------------------------------------------------------------
__global__ __launch_bounds__(256) void proj_gemm(
    const short* __restrict__ Qb, const short* __restrict__ Kb, const short* __restrict__ Vb,
    const short* __restrict__ wqT, const short* __restrict__ wkT, const short* __restrict__ wvT,
    const float* __restrict__ bq, const float* __restrict__ bk, const float* __restrict__ bv,
    short* __restrict__ qbuf, short* __restrict__ kbuf, short* __restrict__ vTbuf)
{
    __shared__ char lds[49152];
    int which = blockIdx.z;
    const short* A  = (which == 0) ? Qb : (which == 1) ? Kb : Vb;
    const short* BT = (which == 0) ? wqT : (which == 1) ? wkT : wvT;
    const float* bias = (which == 0) ? bq : (which == 1) ? bk : bv;

    int rowM0 = blockIdx.x * 128;
    int colN0 = blockIdx.y * 128;

    f32x4 acc[4][4];
    #pragma unroll
    for (int i = 0; i < 4; ++i)
        #pragma unroll
        for (int j = 0; j < 4; ++j) acc[i][j] = (f32x4){0.f, 0.f, 0.f, 0.f};

    gemm_mainloop(A, BT, rowM0, colN0, lds, acc);

    int lane = threadIdx.x & 63, w = threadIdx.x >> 6;
    int l16 = lane & 15, quad = lane >> 4;
    int wm = w >> 1, wn = w & 1;

    if (which == 2) {
        #pragma unroll
        for (int j = 0; j < 4; ++j) {
            int col = colN0 + wn * 64 + j * 16 + l16;
            int hh = col >> 6, dv = col & 63;
            float bs = bias[col];
            #pragma unroll
            for (int i = 0; i < 4; ++i) {
                int rowb = rowM0 + wm * 64 + i * 16 + quad * 4;
                int bb = rowb >> 11, n0 = rowb & 2047;
                s16x4 pk;
                #pragma unroll
                for (int r2 = 0; r2 < 4; ++r2) pk[r2] = f2bs(acc[i][j][r2] + bs);
                *(s16x4*)(vTbuf + (((size_t)bb * H + hh) * DK + dv) * N_ + n0) = pk;
            }
        }
    } else {
        short* dst = (which == 0) ? qbuf : kbuf;
        float scl = (which == 0) ? 0.180336880f : 1.0f;   // 0.125 * log2(e)
        #pragma unroll
        for (int j = 0; j < 4; ++j) {
            int col = colN0 + wn * 64 + j * 16 + l16;
            float bs = bias[col];
            #pragma unroll
            for (int i = 0; i < 4; ++i) {
                int rowb = rowM0 + wm * 64 + i * 16 + quad * 4;
                #pragma unroll
                for (int r2 = 0; r2 < 4; ++r2)
                    dst[(size_t)(rowb + r2) * 1024 + col] = f2bs((acc[i][j][r2] + bs) * scl);
            }
        }
    }
}

// ---------------------------------------------------------------------------
// Output projection (linear grid 64x8)
// ---------------------------------------------------------------------------
__global__ __launch_bounds__(256) void out_gemm(
    const short* __restrict__ obuf, const short* __restrict__ woT,
    const float* __restrict__ bo, float* __restrict__ out)
{
    __shared__ char lds[49152];
    int rowM0 = blockIdx.x * 128;
    int colN0 = blockIdx.y * 128;

    f32x4 acc[4][4];
    #pragma unroll
    for (int i = 0; i < 4; ++i)
        #pragma unroll
        for (int j = 0; j < 4; ++j) acc[i][j] = (f32x4){0.f, 0.f, 0.f, 0.f};

    gemm_mainloop(obuf, woT, rowM0, colN0, lds, acc);

    int lane = threadIdx.x & 63, w = threadIdx.x >> 6;
    int l16 = lane & 15, quad = lane >> 4;
    int wm = w >> 1, wn = w & 1;

    #pragma unroll
    for (int j = 0; j < 4; ++j) {
        int col = colN0 + wn * 64 + j * 16 + l16;
        float bs = bo[col];
        #pragma unroll
        for (int i = 0; i < 4; ++i) {
            int rowb = rowM0 + wm * 64 + i * 16 + quad * 4;
            #pragma unroll
            for (int r2 = 0; r2 < 4; ++r2)
                out[(size_t)(rowb + r2) * 1024 + col] = acc[i][j][r2] + bs;
        }
    }
}

// ---------------------------------------------------------------------------
// Flash attention: REVERTED to the two-pass structure (round 1) — best
// measured (<71.5us). The round-5 merged-pass variant regressed to 84us
// (longer serialized per-iteration chain through the shared P buffer).
// setprio(1) around QK^T and PV MFMA clusters.
// ---------------------------------------------------------------------------
__global__ __launch_bounds__(256) void flash_kernel(
    const short* __restrict__ qbuf, const short* __restrict__ kbuf, const short* __restrict__ vT,
    short* __restrict__ obuf, const int* __restrict__ amask)
{
    __shared__ short Ks[2][4096];        // [key(perm)][dk] swizzled, dbuf
    __shared__ short Vs[2][4096];        // [dv][key] swizzled, dbuf
    __shared__ char  plds[4][2048];      // per-wave P tile 16x64, XOR-swizzled

    int bid = blockIdx.x;
    int g = bid & 7, idx = bid >> 3;
    int bh = g * 8 + (idx >> 4);         // XCD-affinity: one XCD -> 8 bh
    int xq = idx & 15;                   // q-tile pair selector
    int b = bh >> 4, h = bh & 15;

    int tid = threadIdx.x;
    int lane = tid & 63, wave = tid >> 6;
    int l16 = lane & 15, quad = lane >> 4;
    int msk = amask[0];

    int i8 = lane >> 3, i7 = lane & 7;
    int sg = (i7 ^ i8) << 4;
    int pk0 = i8 * 4 + wave;             // permuted K source row for LDS row wave*16+i8
    int skey = wave * 16 + i8;           // V source row (natural)
    int ldst = wave * 2048 + lane * 16;

    const char* kbase = (const char*)(kbuf + (size_t)b * 2048 * 1024 + h * 64);
    const char* vbase = (const char*)(vT + ((size_t)(b * 16 + h) * 64) * 2048);

    int m7 = l16 & 7;
    int g0 = (quad ^ m7) << 4;           // Ks/Vs read slots (row == l16 mod 8)
    int g1 = ((4 | quad) ^ m7) << 4;

    char* pw = plds[wave];
    int prd0 = l16 * 128 + g0;           // P A-frag reads (row = l16)
    int prd1 = l16 * 128 + g1;
    int pwa[4];                          // P write addrs (loop-invariant)
    #pragma unroll
    for (int r = 0; r < 4; ++r) {
        int row = quad * 4 + r;
        pwa[r] = row * 128 + (((l16 >> 1) ^ (row & 7)) << 4) + ((l16 & 1) << 3);
    }

    for (int pass = 0; pass < 2; ++pass) {
        int qt = pass ? (31 - xq) : xq;
        int qw = qt * 64 + wave * 16;
        int nkb = msk ? (qt + 1) : 32;

        const short* qp = qbuf + ((size_t)(b * 2048 + qw + l16)) * 1024 + h * 64;
        bf16x8 aq0 = *(const bf16x8*)(qp + quad * 8);
        bf16x8 aq1 = *(const bf16x8*)(qp + 32 + quad * 8);

        f32x4 o[4];
        float lsum[4];
        #pragma unroll
        for (int i = 0; i < 4; ++i) { o[i] = (f32x4){0.f, 0.f, 0.f, 0.f}; lsum[i] = 0.f; }

        // stage tile 0 into buffer 0
        async16(kbase + (size_t)pk0 * 2048 + sg, (char*)Ks[0] + ldst);
        async16(kbase + (size_t)(pk0 + 32) * 2048 + sg, (char*)Ks[0] + ldst + 1024);
        async16(vbase + (size_t)skey * 4096 + sg, (char*)Vs[0] + ldst);
        async16(vbase + (size_t)(skey + 8) * 4096 + sg, (char*)Vs[0] + ldst + 1024);

        for (int ib = 0; ib < nkb; ++ib) {
            __syncthreads();             // publishes buf[ib&1]
            int cur = ib & 1;
            if (ib + 1 < nkb) {
                int nb = (ib + 1) & 1;
                size_t kb2 = (size_t)(ib + 1) * 64;
                async16(kbase + (kb2 + pk0) * 2048 + sg, (char*)Ks[nb] + ldst);
                async16(kbase + (kb2 + pk0 + 32) * 2048 + sg, (char*)Ks[nb] + ldst + 1024);
                async16(vbase + (size_t)skey * 4096 + kb2 * 2 + sg, (char*)Vs[nb] + ldst);
                async16(vbase + (size_t)(skey + 8) * 4096 + kb2 * 2 + sg, (char*)Vs[nb] + ldst + 1024);
            }
            int kb = ib * 64;

            // S = q K^T (log2 domain; S column (nt,l16) = key 4*l16+nt)
            f32x4 s[4];
            __builtin_amdgcn_s_setprio(1);
            #pragma unroll
            for (int nt = 0; nt < 4; ++nt) {
                const char* kr = (const char*)Ks[cur] + (nt * 16 + l16) * 128;
                bf16x8 b0 = *(const bf16x8*)(kr + g0);
                bf16x8 b1 = *(const bf16x8*)(kr + g1);
                f32x4 t = (f32x4){0.f, 0.f, 0.f, 0.f};
                t = __builtin_amdgcn_mfma_f32_16x16x32_bf16(aq0, b0, t, 0, 0, 0);
                t = __builtin_amdgcn_mfma_f32_16x16x32_bf16(aq1, b1, t, 0, 0, 0);
                s[nt] = t;
            }
            __builtin_amdgcn_s_setprio(0);

            if (msk && (kb + 63 > qw)) {
                #pragma unroll
                for (int r = 0; r < 4; ++r) {
                    int row = qw + quad * 4 + r;
                    #pragma unroll
                    for (int nt = 0; nt < 4; ++nt) {
                        int col = kb + l16 * 4 + nt;
                        if (col > row) s[nt][r] = -3e38f;
                    }
                }
            }

            // p = exp2(s); truncation-pack to bf16 via v_perm; defer row sums
            __builtin_amdgcn_wave_barrier();
            #pragma unroll
            for (int r = 0; r < 4; ++r) {
                float p0 = __builtin_amdgcn_exp2f(s[0][r]);
                float p1 = __builtin_amdgcn_exp2f(s[1][r]);
                float p2 = __builtin_amdgcn_exp2f(s[2][r]);
                float p3 = __builtin_amdgcn_exp2f(s[3][r]);
                lsum[r] += (p0 + p1) + (p2 + p3);
                u32x2 pk;
                pk[0] = packbf(p0, p1);
                pk[1] = packbf(p2, p3);
                *(u32x2*)(pw + pwa[r]) = pk;
            }
            __builtin_amdgcn_wave_barrier();
            bf16x8 ap0 = *(const bf16x8*)(pw + prd0);
            bf16x8 ap1 = *(const bf16x8*)(pw + prd1);
            __builtin_amdgcn_wave_barrier();

            // O += P V (natural key order on both sides)
            __builtin_amdgcn_s_setprio(1);
            #pragma unroll
            for (int vb = 0; vb < 4; ++vb) {
                const char* vr = (const char*)Vs[cur] + (vb * 16 + l16) * 128;
                bf16x8 v0 = *(const bf16x8*)(vr + g0);
                bf16x8 v1 = *(const bf16x8*)(vr + g1);
                o[vb] = __builtin_amdgcn_mfma_f32_16x16x32_bf16(ap0, v0, o[vb], 0, 0, 0);
                o[vb] = __builtin_amdgcn_mfma_f32_16x16x32_bf16(ap1, v1, o[vb], 0, 0, 0);
            }
            __builtin_amdgcn_s_setprio(0);
        }

        // epilogue: reduce row sums across 16 col-lanes, normalize, store
        #pragma unroll
        for (int r = 0; r < 4; ++r) {
            float t = lsum[r];
            #pragma unroll
            for (int off = 1; off < 16; off <<= 1) t += __shfl_xor(t, off, 64);
            float inv = 1.0f / t;
            int row = qw + quad * 4 + r;
            #pragma unroll
            for (int vb = 0; vb < 4; ++vb)
                obuf[((size_t)(b * 2048 + row)) * 1024 + h * 64 + vb * 16 + l16] =
                    f2bs(o[vb][r] * inv);
        }
        __syncthreads();   // pass boundary: K/V buffers safe to restage
    }
}

// ---------------------------------------------------------------------------
extern "C" void kernel_launch(void* const* d_in, const int* in_sizes, int n_in,
                              void* d_out, int out_size, void* d_ws, size_t ws_size,
                              hipStream_t stream)
{
    const float* Q  = (const float*)d_in[0];
    const float* K  = (const float*)d_in[1];
    const float* V  = (const float*)d_in[2];
    const float* Wq = (const float*)d_in[3];
    const float* bq = (const float*)d_in[4];
    const float* Wk = (const float*)d_in[5];
    const float* bk = (const float*)d_in[6];
    const float* Wv = (const float*)d_in[7];
    const float* bv = (const float*)d_in[8];
    const float* Wo = (const float*)d_in[9];
    const float* bo = (const float*)d_in[10];
    const int* amask = (const int*)d_in[11];
    float* out = (float*)d_out;

    char* ws = (char*)d_ws;
    const size_t SZ = (size_t)B_ * N_ * DM * sizeof(short);      // 16 MiB each
    const size_t SZW = (size_t)H * DK * DM * sizeof(short);      // 2 MiB each
    short* Qb    = (short*)ws; ws += SZ;       // reused as obuf after proj
    short* Kb    = (short*)ws; ws += SZ;
    short* Vb    = (short*)ws; ws += SZ;
    short* qbuf  = (short*)ws; ws += SZ;
    short* kbuf  = (short*)ws; ws += SZ;
    short* vTbuf = (short*)ws; ws += SZ;
    short* wqT   = (short*)ws; ws += SZW;
    short* wkT   = (short*)ws; ws += SZW;
    short* wvT   = (short*)ws; ws += SZW;
    short* woT   = (short*)ws; ws += SZW;
    short* obuf  = Qb;

    prep_kernel<<<dim3(4096, 4), dim3(256), 0, stream>>>(Q, K, V, Wq, Wk, Wv, Wo,
                                                         Qb, Kb, Vb, wqT, wkT, wvT, woT);
    proj_gemm<<<dim3(64, 8, 3), dim3(256), 0, stream>>>(Qb, Kb, Vb, wqT, wkT, wvT,
                                                        bq, bk, bv, qbuf, kbuf, vTbuf);
    flash_kernel<<<dim3(1024), dim3(256), 0, stream>>>(qbuf, kbuf, vTbuf, obuf, amask);
    out_gemm<<<dim3(64, 8), dim3(256), 0, stream>>>(obuf, woT, bo, out);
}